// Round 1
// baseline (125.140 us; speedup 1.0000x reference)
//
#include <hip/hip_runtime.h>

typedef __attribute__((ext_vector_type(8))) short bf16x8;
typedef __attribute__((ext_vector_type(8))) unsigned short ushort8;
typedef __attribute__((ext_vector_type(4))) float f32x4;

static __device__ __forceinline__ unsigned short f2bf(float f) {
  union { float f; unsigned u; } v; v.f = f;
  unsigned r = v.u + 0x7FFFu + ((v.u >> 16) & 1u);
  return (unsigned short)(r >> 16);
}

// ---------------- fp32 -> bf16 convert (n % 4 == 0) ----------------
__global__ void cvt_kernel(const float* __restrict__ in,
                           unsigned short* __restrict__ out, int n) {
  int idx = (blockIdx.x * blockDim.x + threadIdx.x) * 4;
  int stride = gridDim.x * blockDim.x * 4;
  for (int i = idx; i < n; i += stride) {
    float4 v = *reinterpret_cast<const float4*>(in + i);
    ushort4 o;
    o.x = f2bf(v.x); o.y = f2bf(v.y); o.z = f2bf(v.z); o.w = f2bf(v.w);
    *reinterpret_cast<ushort4*>(out + i) = o;
  }
}

// ---------------- GEMM: C[M][N] = A[M][K](bf16) * B[N][K](bf16)^T + bias ----------------
// 128x128 tile, BK=32, 4 waves each 64x64. OUT_BF16: 1 -> bf16 out, 0 -> fp32 out.
template <int OUT_BF16>
__global__ __launch_bounds__(256) void gemm_bt(
    const unsigned short* __restrict__ A, const unsigned short* __restrict__ B,
    const float* __restrict__ bias, void* __restrict__ Cv,
    int M, int N, int K) {
  __shared__ unsigned short As[128][40];  // +8 pad: conflict-free b128 reads
  __shared__ unsigned short Bs[128][40];
  const int tid = threadIdx.x;
  const int lane = tid & 63;
  const int wid = tid >> 6;
  const int bm = blockIdx.y * 128;
  const int bn = blockIdx.x * 128;
  const int wr = (wid >> 1) * 64;
  const int wc = (wid & 1) * 64;
  const int row16 = lane & 15;
  const int kgrp = lane >> 4;
  const int srow = tid >> 1;
  const int scol = (tid & 1) * 16;

  f32x4 acc[4][4] = {};

  const unsigned short* aptr = A + (size_t)(bm + srow) * K + scol;
  const unsigned short* bptr = B + (size_t)(bn + srow) * K + scol;

  for (int k0 = 0; k0 < K; k0 += 32) {
    ushort8 av0 = *reinterpret_cast<const ushort8*>(aptr + k0);
    ushort8 av1 = *reinterpret_cast<const ushort8*>(aptr + k0 + 8);
    ushort8 bv0 = *reinterpret_cast<const ushort8*>(bptr + k0);
    ushort8 bv1 = *reinterpret_cast<const ushort8*>(bptr + k0 + 8);
    *reinterpret_cast<ushort8*>(&As[srow][scol]) = av0;
    *reinterpret_cast<ushort8*>(&As[srow][scol + 8]) = av1;
    *reinterpret_cast<ushort8*>(&Bs[srow][scol]) = bv0;
    *reinterpret_cast<ushort8*>(&Bs[srow][scol + 8]) = bv1;
    __syncthreads();
    bf16x8 af[4], bfr[4];
    for (int mi = 0; mi < 4; ++mi)
      af[mi] = *reinterpret_cast<const bf16x8*>(&As[wr + mi * 16 + row16][kgrp * 8]);
    for (int ni = 0; ni < 4; ++ni)
      bfr[ni] = *reinterpret_cast<const bf16x8*>(&Bs[wc + ni * 16 + row16][kgrp * 8]);
    for (int mi = 0; mi < 4; ++mi)
      for (int ni = 0; ni < 4; ++ni)
        acc[mi][ni] = __builtin_amdgcn_mfma_f32_16x16x32_bf16(af[mi], bfr[ni],
                                                              acc[mi][ni], 0, 0, 0);
    __syncthreads();
  }

  // Epilogue. C/D layout: col = lane&15, row = (lane>>4)*4 + reg  [m89-verified]
  for (int ni = 0; ni < 4; ++ni) {
    const int gcol = bn + wc + ni * 16 + row16;
    const float bv = bias[gcol];
    for (int mi = 0; mi < 4; ++mi) {
      for (int r = 0; r < 4; ++r) {
        const int grow = bm + wr + mi * 16 + kgrp * 4 + r;
        const float val = acc[mi][ni][r] + bv;
        if (OUT_BF16)
          reinterpret_cast<unsigned short*>(Cv)[(size_t)grow * N + gcol] = f2bf(val);
        else
          reinterpret_cast<float*>(Cv)[(size_t)grow * N + gcol] = val;
      }
    }
  }
}

// ---------------- local (banded) attention ----------------
// qkv: [B*S][1536] bf16  (q: 0..511, k: 512..1023, v: 1024..1535; head h at h*64)
// ctx: [B*S][512] bf16
// grid: (S/64, B*H). Block: 256 thr = 4 waves; wave w owns queries q0+16w..+15.
__global__ __launch_bounds__(256) void attn_local(
    const unsigned short* __restrict__ qkv, unsigned short* __restrict__ ctx,
    int S) {
  __shared__ unsigned short Ks[128][72];   // keys q0-32..q0+95, [key][d], +8 pad
  __shared__ unsigned short Vt[64][152];   // [d][key] transposed; cols 128..151 zeroed
  __shared__ unsigned short Ps[4][16][104];// per-wave P, [qrow][key 0..95]

  const int tid = threadIdx.x;
  const int lane = tid & 63;
  const int wid = tid >> 6;
  const int q0 = blockIdx.x * 64;
  const int bh = blockIdx.y;
  const int b = bh >> 3;
  const int h = bh & 7;

  // ---- stage K and transposed V ----
  {
    const int i = tid >> 1;           // window key index 0..127
    const int dseg = (tid & 1) * 32;  // d offset 0/32
    const int kk = q0 - 32 + i;
    ushort8 kv[4], vv[4];
    const ushort8 zero8 = {0, 0, 0, 0, 0, 0, 0, 0};
    if (kk >= 0 && kk < S) {
      const unsigned short* kp =
          qkv + (size_t)(b * S + kk) * 1536 + 512 + h * 64 + dseg;
      const unsigned short* vp = kp + 512;
      for (int j = 0; j < 4; ++j) kv[j] = reinterpret_cast<const ushort8*>(kp)[j];
      for (int j = 0; j < 4; ++j) vv[j] = reinterpret_cast<const ushort8*>(vp)[j];
    } else {
      for (int j = 0; j < 4; ++j) { kv[j] = zero8; vv[j] = zero8; }
    }
    for (int j = 0; j < 4; ++j)
      *reinterpret_cast<ushort8*>(&Ks[i][dseg + j * 8]) = kv[j];
    for (int j = 0; j < 32; ++j) Vt[dseg + j][i] = vv[j >> 3][j & 7];
    // zero Vt tail cols 128..151 (read by the padded 96-key PV window)
    const int zr = tid >> 2;
    const int zc = 128 + (tid & 3) * 6;
    for (int j = 0; j < 6; ++j) Vt[zr][zc + j] = 0;
  }

  // ---- Q fragments (from global; A-frag: lane holds Q[row16][kgrp*8+j]) ----
  const int row16 = lane & 15;
  const int kgrp = lane >> 4;
  bf16x8 qf[2];
  {
    const int qrow = q0 + wid * 16 + row16;
    const unsigned short* qp = qkv + (size_t)(b * S + qrow) * 1536 + h * 64;
    qf[0] = *reinterpret_cast<const bf16x8*>(qp + kgrp * 8);
    qf[1] = *reinterpret_cast<const bf16x8*>(qp + 32 + kgrp * 8);
  }
  __syncthreads();

  // ---- scores: 5 key tiles at offsets -32..+32 relative to query tile ----
  f32x4 sc[5];
  for (int t = 0; t < 5; ++t) {
    const int kbase = (wid + t) * 16;  // LDS key index base
    bf16x8 kf0 = *reinterpret_cast<const bf16x8*>(&Ks[kbase + row16][kgrp * 8]);
    bf16x8 kf1 = *reinterpret_cast<const bf16x8*>(&Ks[kbase + row16][32 + kgrp * 8]);
    f32x4 s = {0.f, 0.f, 0.f, 0.f};
    s = __builtin_amdgcn_mfma_f32_16x16x32_bf16(qf[0], kf0, s, 0, 0, 0);
    s = __builtin_amdgcn_mfma_f32_16x16x32_bf16(qf[1], kf1, s, 0, 0, 0);
    sc[t] = s;
  }

  // ---- mask + softmax (rows live across the 16 lanes of each lane-group) ----
  const int ccol = row16;      // key col within tile (C/D: col = lane&15)
  const int crow4 = kgrp * 4;  // query row base (C/D: row = (lane>>4)*4+reg)
  float rm[4] = {-INFINITY, -INFINITY, -INFINITY, -INFINITY};
  for (int t = 0; t < 5; ++t)
    for (int r = 0; r < 4; ++r) {
      const int key_abs = q0 - 32 + (wid + t) * 16 + ccol;
      const int diff = -32 + t * 16 + ccol - crow4 - r;
      float s = sc[t][r] * 0.125f;  // 1/sqrt(64)
      const bool valid = (diff >= -32) && (diff <= 32) && (key_abs >= 0) && (key_abs < S);
      s = valid ? s : -INFINITY;
      sc[t][r] = s;
      rm[r] = fmaxf(rm[r], s);
    }
  for (int off = 1; off < 16; off <<= 1)
    for (int r = 0; r < 4; ++r) rm[r] = fmaxf(rm[r], __shfl_xor(rm[r], off, 64));
  float rs[4] = {0.f, 0.f, 0.f, 0.f};
  for (int t = 0; t < 5; ++t)
    for (int r = 0; r < 4; ++r) {
      const float p = __expf(sc[t][r] - rm[r]);
      sc[t][r] = p;
      rs[r] += p;
    }
  for (int off = 1; off < 16; off <<= 1)
    for (int r = 0; r < 4; ++r) rs[r] += __shfl_xor(rs[r], off, 64);

  // ---- P -> LDS (bf16), pad keys 80..95 with zeros ----
  for (int t = 0; t < 5; ++t)
    for (int r = 0; r < 4; ++r)
      Ps[wid][crow4 + r][t * 16 + ccol] = f2bf(sc[t][r]);
  for (int j = 0; j < 4; ++j) Ps[wid][row16][80 + kgrp * 4 + j] = 0;
  __syncthreads();

  // ---- PV: ctx[16x64] = P[16x96] * V[96x64] ----
  f32x4 cacc[4] = {};
  for (int kc = 0; kc < 3; ++kc) {
    bf16x8 pf = *reinterpret_cast<const bf16x8*>(&Ps[wid][row16][kc * 32 + kgrp * 8]);
    for (int ni = 0; ni < 4; ++ni) {
      bf16x8 vf = *reinterpret_cast<const bf16x8*>(
          &Vt[ni * 16 + row16][wid * 16 + kc * 32 + kgrp * 8]);
      cacc[ni] = __builtin_amdgcn_mfma_f32_16x16x32_bf16(pf, vf, cacc[ni], 0, 0, 0);
    }
  }

  // ---- normalize + store ----
  float inv[4];
  for (int r = 0; r < 4; ++r) inv[r] = 1.0f / rs[r];
  for (int ni = 0; ni < 4; ++ni)
    for (int r = 0; r < 4; ++r) {
      const size_t off =
          (size_t)(b * S + q0 + wid * 16 + crow4 + r) * 512 + h * 64 + ni * 16 + ccol;
      ctx[off] = f2bf(cacc[ni][r] * inv[r]);
    }
}

extern "C" void kernel_launch(void* const* d_in, const int* in_sizes, int n_in,
                              void* d_out, int out_size, void* d_ws, size_t ws_size,
                              hipStream_t stream) {
  const float* x = (const float*)d_in[0];
  const float* w_in = (const float*)d_in[1];
  const float* b_in = (const float*)d_in[2];
  const float* w_out = (const float*)d_in[3];
  const float* b_out = (const float*)d_in[4];
  float* out = (float*)d_out;

  const int B = 2, S = 4096, D = 512;
  const int BS = B * S;  // 8192

  // workspace layout (bytes), all 16B-aligned
  char* ws = (char*)d_ws;
  unsigned short* xb = (unsigned short*)(ws + 0);          //  8,388,608
  unsigned short* wbin = (unsigned short*)(ws + 8388608);  //  1,572,864
  unsigned short* wbo = (unsigned short*)(ws + 9961472);   //    524,288
  unsigned short* qkvb = (unsigned short*)(ws + 10485760); // 25,165,824
  unsigned short* ctxb = (unsigned short*)(ws + 35651584); //  8,388,608

  cvt_kernel<<<1024, 256, 0, stream>>>(x, xb, BS * D);
  cvt_kernel<<<512, 256, 0, stream>>>(w_in, wbin, 3 * D * D);
  cvt_kernel<<<256, 256, 0, stream>>>(w_out, wbo, D * D);

  // QKV projection: [8192,512] x [1536,512]^T -> bf16 [8192,1536]
  gemm_bt<1><<<dim3(12, 64), 256, 0, stream>>>(xb, wbin, b_in, qkvb, BS, 3 * D, D);

  // local attention -> ctx bf16 [8192,512]
  attn_local<<<dim3(S / 64, 16), 256, 0, stream>>>(qkvb, ctxb, S);

  // out projection: [8192,512] x [512,512]^T -> fp32 d_out
  gemm_bt<0><<<dim3(4, 64), 256, 0, stream>>>(ctxb, wbo, b_out, out, BS, D, D);
}

// Round 3
// 68.925 us; speedup vs baseline: 1.8156x; 1.8156x over previous
//
#include <hip/hip_runtime.h>

typedef __attribute__((ext_vector_type(8))) short bf16x8;
typedef __attribute__((ext_vector_type(8))) unsigned short ushort8;
typedef __attribute__((ext_vector_type(4))) float f32x4;

static __device__ __forceinline__ unsigned short f2bf(float f) {
  union { float f; unsigned u; } v; v.f = f;
  unsigned r = v.u + 0x7FFFu + ((v.u >> 16) & 1u);
  return (unsigned short)(r >> 16);
}
static __device__ __forceinline__ int iclamp(int x, int lo, int hi) {
  return x < lo ? lo : (x > hi ? hi : x);
}

// ---------------- fp32 -> bf16 convert (n % 4 == 0) ----------------
__global__ void cvt_kernel(const float* __restrict__ in,
                           unsigned short* __restrict__ out, int n) {
  int idx = (blockIdx.x * blockDim.x + threadIdx.x) * 4;
  int stride = gridDim.x * blockDim.x * 4;
  for (int i = idx; i < n; i += stride) {
    float4 v = *reinterpret_cast<const float4*>(in + i);
    ushort4 o;
    o.x = f2bf(v.x); o.y = f2bf(v.y); o.z = f2bf(v.z); o.w = f2bf(v.w);
    *reinterpret_cast<ushort4*>(out + i) = o;
  }
}

// ---------------- GEMM: C[M][N] = A[M][K](bf16) * B[N][K](bf16)^T + bias ----------------
template <int OUT_BF16>
__global__ __launch_bounds__(256) void gemm_bt(
    const unsigned short* __restrict__ A, const unsigned short* __restrict__ B,
    const float* __restrict__ bias, void* __restrict__ Cv,
    int M, int N, int K) {
  __shared__ unsigned short As[128][40];
  __shared__ unsigned short Bs[128][40];
  const int tid = threadIdx.x;
  const int lane = tid & 63;
  const int wid = tid >> 6;
  const int bm = blockIdx.y * 128;
  const int bn = blockIdx.x * 128;
  const int wr = (wid >> 1) * 64;
  const int wc = (wid & 1) * 64;
  const int row16 = lane & 15;
  const int kgrp = lane >> 4;
  const int srow = tid >> 1;
  const int scol = (tid & 1) * 16;

  f32x4 acc[4][4] = {};

  const unsigned short* aptr = A + (size_t)(bm + srow) * K + scol;
  const unsigned short* bptr = B + (size_t)(bn + srow) * K + scol;

  for (int k0 = 0; k0 < K; k0 += 32) {
    ushort8 av0 = *reinterpret_cast<const ushort8*>(aptr + k0);
    ushort8 av1 = *reinterpret_cast<const ushort8*>(aptr + k0 + 8);
    ushort8 bv0 = *reinterpret_cast<const ushort8*>(bptr + k0);
    ushort8 bv1 = *reinterpret_cast<const ushort8*>(bptr + k0 + 8);
    *reinterpret_cast<ushort8*>(&As[srow][scol]) = av0;
    *reinterpret_cast<ushort8*>(&As[srow][scol + 8]) = av1;
    *reinterpret_cast<ushort8*>(&Bs[srow][scol]) = bv0;
    *reinterpret_cast<ushort8*>(&Bs[srow][scol + 8]) = bv1;
    __syncthreads();
    bf16x8 af[4], bfr[4];
#pragma unroll
    for (int mi = 0; mi < 4; ++mi)
      af[mi] = *reinterpret_cast<const bf16x8*>(&As[wr + mi * 16 + row16][kgrp * 8]);
#pragma unroll
    for (int ni = 0; ni < 4; ++ni)
      bfr[ni] = *reinterpret_cast<const bf16x8*>(&Bs[wc + ni * 16 + row16][kgrp * 8]);
#pragma unroll
    for (int mi = 0; mi < 4; ++mi)
#pragma unroll
      for (int ni = 0; ni < 4; ++ni)
        acc[mi][ni] = __builtin_amdgcn_mfma_f32_16x16x32_bf16(af[mi], bfr[ni],
                                                              acc[mi][ni], 0, 0, 0);
    __syncthreads();
  }

#pragma unroll
  for (int ni = 0; ni < 4; ++ni) {
    const int gcol = bn + wc + ni * 16 + row16;
    const float bv = bias[gcol];
#pragma unroll
    for (int mi = 0; mi < 4; ++mi) {
#pragma unroll
      for (int r = 0; r < 4; ++r) {
        const int grow = bm + wr + mi * 16 + kgrp * 4 + r;
        const float val = acc[mi][ni][r] + bv;
        if (OUT_BF16)
          reinterpret_cast<unsigned short*>(Cv)[(size_t)grow * N + gcol] = f2bf(val);
        else
          reinterpret_cast<float*>(Cv)[(size_t)grow * N + gcol] = val;
      }
    }
  }
}

// ---------------- local (banded) attention, v3 ----------------
// qkv: [B*S][1536] bf16 (q:0..511, k:512..1023, v:1024..1535; head h at h*64)
// ctx: [B*S][512] bf16
// grid: (S/64, B*H), block 256 = 4 waves; wave w owns queries q0+16w..+15.
// K/Q fragments read directly from global (clamped rows; masking fixes edges).
// V staged transposed in LDS as packed key-pairs: Vt[d][k2] = V[2k2][d] | V[2k2+1][d]<<16.
// Row width 76 dwords: keys 0..127 in dwords 0..63; dwords 64..71 ZEROED
// (PV reads up to dword 71 for wave 3's zero-P tail keys — must be finite!).
__global__ __launch_bounds__(256) void attn_local(
    const unsigned short* __restrict__ qkv, unsigned short* __restrict__ ctx,
    int S) {
  __shared__ unsigned Vt[64][76];            // 19456 B; stride 304B (16B-aligned)
  __shared__ unsigned short Ps[4][16][104];  // 13312 B

  const int tid = threadIdx.x;
  const int lane = tid & 63;
  const int wid = tid >> 6;
  const int q0 = blockIdx.x * 64;
  const int b = blockIdx.y >> 3;
  const int h = blockIdx.y & 7;
  const int row16 = lane & 15;
  const int kgrp = lane >> 4;
  const size_t bS = (size_t)b * S;

  // ---- stage V transposed (packed key pairs), fully vectorized ----
  {
    const int k2 = tid >> 2;          // key pair 0..63 (window keys 2k2, 2k2+1)
    const int dq = (tid & 3) * 16;    // d range [dq, dq+15]
    const int ra = iclamp(q0 - 32 + 2 * k2, 0, S - 1);
    const int rb = iclamp(q0 - 32 + 2 * k2 + 1, 0, S - 1);
    const unsigned short* pa = qkv + (bS + ra) * 1536 + 1024 + h * 64 + dq;
    const unsigned short* pb = qkv + (bS + rb) * 1536 + 1024 + h * 64 + dq;
    ushort8 a0 = reinterpret_cast<const ushort8*>(pa)[0];
    ushort8 a1 = reinterpret_cast<const ushort8*>(pa)[1];
    ushort8 b0 = reinterpret_cast<const ushort8*>(pb)[0];
    ushort8 b1 = reinterpret_cast<const ushort8*>(pb)[1];
#pragma unroll
    for (int d = 0; d < 8; ++d) {
      Vt[dq + d][k2] = (unsigned)a0[d] | ((unsigned)b0[d] << 16);
      Vt[dq + 8 + d][k2] = (unsigned)a1[d] | ((unsigned)b1[d] << 16);
    }
    // zero tail dwords 64..71 (window keys 128..143; P=0 there but MFMA
    // must see finite operands: 0 x NaN = NaN was round-2's failure)
    const int zr = tid >> 2;
    const int zc = 64 + (tid & 3) * 2;
    Vt[zr][zc] = 0u;
    Vt[zr][zc + 1] = 0u;
  }

  // ---- Q fragments (direct from global) ----
  bf16x8 qf0, qf1;
  {
    const unsigned short* qp =
        qkv + (bS + q0 + wid * 16 + row16) * 1536 + h * 64;
    qf0 = *reinterpret_cast<const bf16x8*>(qp + kgrp * 8);
    qf1 = *reinterpret_cast<const bf16x8*>(qp + 32 + kgrp * 8);
  }

  // ---- QK^T: 5 key tiles, K fragments direct from global (clamped) ----
  f32x4 sc[5];
#pragma unroll
  for (int t = 0; t < 5; ++t) {
    const int key = iclamp(q0 - 32 + (wid + t) * 16 + row16, 0, S - 1);
    const unsigned short* kp = qkv + (bS + key) * 1536 + 512 + h * 64;
    bf16x8 kf0 = *reinterpret_cast<const bf16x8*>(kp + kgrp * 8);
    bf16x8 kf1 = *reinterpret_cast<const bf16x8*>(kp + 32 + kgrp * 8);
    f32x4 s = {0.f, 0.f, 0.f, 0.f};
    s = __builtin_amdgcn_mfma_f32_16x16x32_bf16(qf0, kf0, s, 0, 0, 0);
    s = __builtin_amdgcn_mfma_f32_16x16x32_bf16(qf1, kf1, s, 0, 0, 0);
    sc[t] = s;
  }

  // ---- mask + softmax (C/D: col=lane&15 -> key, row=(lane>>4)*4+r -> query) ----
  const int ccol = row16;
  const int crow4 = kgrp * 4;
  float rm[4] = {-INFINITY, -INFINITY, -INFINITY, -INFINITY};
#pragma unroll
  for (int t = 0; t < 5; ++t)
#pragma unroll
    for (int r = 0; r < 4; ++r) {
      const int key_abs = q0 - 32 + (wid + t) * 16 + ccol;
      const int diff = -32 + t * 16 + ccol - crow4 - r;
      float s = sc[t][r] * 0.125f;  // 1/sqrt(64)
      const bool valid =
          (diff >= -32) && (diff <= 32) && (key_abs >= 0) && (key_abs < S);
      s = valid ? s : -INFINITY;
      sc[t][r] = s;
      rm[r] = fmaxf(rm[r], s);
    }
#pragma unroll
  for (int off = 1; off < 16; off <<= 1)
#pragma unroll
    for (int r = 0; r < 4; ++r) rm[r] = fmaxf(rm[r], __shfl_xor(rm[r], off, 64));
  float rs[4] = {0.f, 0.f, 0.f, 0.f};
#pragma unroll
  for (int t = 0; t < 5; ++t)
#pragma unroll
    for (int r = 0; r < 4; ++r) {
      const float p = __expf(sc[t][r] - rm[r]);
      sc[t][r] = p;
      rs[r] += p;
    }
#pragma unroll
  for (int off = 1; off < 16; off <<= 1)
#pragma unroll
    for (int r = 0; r < 4; ++r) rs[r] += __shfl_xor(rs[r], off, 64);

  // ---- P -> LDS (bf16), zero-pad keys 80..95 ----
#pragma unroll
  for (int t = 0; t < 5; ++t)
#pragma unroll
    for (int r = 0; r < 4; ++r)
      Ps[wid][crow4 + r][t * 16 + ccol] = f2bf(sc[t][r]);
#pragma unroll
  for (int j = 0; j < 4; ++j) Ps[wid][row16][80 + kgrp * 4 + j] = 0;

  __syncthreads();  // Vt (cross-wave) + Ps (own-wave) now visible

  // ---- PV: ctx[16x64] = P[16x96] * V[96x64] ----
  f32x4 cacc[4] = {};
#pragma unroll
  for (int kc = 0; kc < 3; ++kc) {
    bf16x8 pf = *reinterpret_cast<const bf16x8*>(&Ps[wid][row16][kc * 32 + kgrp * 8]);
#pragma unroll
    for (int ni = 0; ni < 4; ++ni) {
      // dword idx -> keys wid*16 + kc*32 + kgrp*8 .. +7 at d = ni*16+row16
      bf16x8 vf = *reinterpret_cast<const bf16x8*>(
          &Vt[ni * 16 + row16][wid * 8 + kc * 16 + kgrp * 4]);
      cacc[ni] = __builtin_amdgcn_mfma_f32_16x16x32_bf16(pf, vf, cacc[ni], 0, 0, 0);
    }
  }

  // ---- normalize + store ----
  float inv[4];
#pragma unroll
  for (int r = 0; r < 4; ++r) inv[r] = 1.0f / rs[r];
#pragma unroll
  for (int ni = 0; ni < 4; ++ni)
#pragma unroll
    for (int r = 0; r < 4; ++r) {
      const size_t off =
          (bS + q0 + wid * 16 + crow4 + r) * 512 + h * 64 + ni * 16 + ccol;
      ctx[off] = f2bf(cacc[ni][r] * inv[r]);
    }
}

extern "C" void kernel_launch(void* const* d_in, const int* in_sizes, int n_in,
                              void* d_out, int out_size, void* d_ws, size_t ws_size,
                              hipStream_t stream) {
  const float* x = (const float*)d_in[0];
  const float* w_in = (const float*)d_in[1];
  const float* b_in = (const float*)d_in[2];
  const float* w_out = (const float*)d_in[3];
  const float* b_out = (const float*)d_in[4];
  float* out = (float*)d_out;

  const int B = 2, S = 4096, D = 512;
  const int BS = B * S;  // 8192

  char* ws = (char*)d_ws;
  unsigned short* xb = (unsigned short*)(ws + 0);          //  8,388,608
  unsigned short* wbin = (unsigned short*)(ws + 8388608);  //  1,572,864
  unsigned short* wbo = (unsigned short*)(ws + 9961472);   //    524,288
  unsigned short* qkvb = (unsigned short*)(ws + 10485760); // 25,165,824
  unsigned short* ctxb = (unsigned short*)(ws + 35651584); //  8,388,608

  cvt_kernel<<<1024, 256, 0, stream>>>(x, xb, BS * D);
  cvt_kernel<<<512, 256, 0, stream>>>(w_in, wbin, 3 * D * D);
  cvt_kernel<<<256, 256, 0, stream>>>(w_out, wbo, D * D);

  // QKV projection: [8192,512] x [1536,512]^T -> bf16 [8192,1536]
  gemm_bt<1><<<dim3(12, 64), 256, 0, stream>>>(xb, wbin, b_in, qkvb, BS, 3 * D, D);

  // local attention -> ctx bf16 [8192,512]
  attn_local<<<dim3(S / 64, 16), 256, 0, stream>>>(qkvb, ctxb, S);

  // out projection: [8192,512] x [512,512]^T -> fp32 d_out
  gemm_bt<0><<<dim3(4, 64), 256, 0, stream>>>(ctxb, wbo, b_out, out, BS, D, D);
}

// Round 4
// 66.586 us; speedup vs baseline: 1.8794x; 1.0351x over previous
//
#include <hip/hip_runtime.h>

typedef __attribute__((ext_vector_type(8))) short bf16x8;
typedef __attribute__((ext_vector_type(8))) unsigned short ushort8;
typedef __attribute__((ext_vector_type(4))) float f32x4;

static __device__ __forceinline__ unsigned short f2bf(float f) {
  union { float f; unsigned u; } v; v.f = f;
  unsigned r = v.u + 0x7FFFu + ((v.u >> 16) & 1u);
  return (unsigned short)(r >> 16);
}
static __device__ __forceinline__ int iclamp(int x, int lo, int hi) {
  return x < lo ? lo : (x > hi ? hi : x);
}
// async global->LDS, 16B per lane; LDS dest = wave-uniform base + lane*16
static __device__ __forceinline__ void gl_lds16(const unsigned short* g,
                                                unsigned short* l) {
  __builtin_amdgcn_global_load_lds(
      (const __attribute__((address_space(1))) void*)g,
      (__attribute__((address_space(3))) void*)l, 16, 0, 0);
}

// ---------------- fp32 -> bf16 convert (n % 4 == 0) ----------------
__global__ void cvt_kernel(const float* __restrict__ in,
                           unsigned short* __restrict__ out, int n) {
  int idx = (blockIdx.x * blockDim.x + threadIdx.x) * 4;
  int stride = gridDim.x * blockDim.x * 4;
  for (int i = idx; i < n; i += stride) {
    float4 v = *reinterpret_cast<const float4*>(in + i);
    ushort4 o;
    o.x = f2bf(v.x); o.y = f2bf(v.y); o.z = f2bf(v.z); o.w = f2bf(v.w);
    *reinterpret_cast<ushort4*>(out + i) = o;
  }
}

// ---------------- GEMM: C[M][N] = A[M][K](bf16) * B[N][K](bf16)^T + bias ----------
// m97 structure: 128x128 tile, BK=32, linear LDS, global_load_lds width-16 staging,
// 4 waves each 64x64, 2 barriers per K-step. Bijective XCD swizzle on block id.
template <int OUT_BF16>
__global__ __launch_bounds__(256) void gemm_bt(
    const unsigned short* __restrict__ A, const unsigned short* __restrict__ B,
    const float* __restrict__ bias, void* __restrict__ Cv,
    int M, int N, int K) {
  __shared__ unsigned short As[128][32];  // linear: global_load_lds needs no pad
  __shared__ unsigned short Bs[128][32];
  const int tid = threadIdx.x;
  const int lane = tid & 63;
  const int wid = tid >> 6;

  // XCD-aware bijective swizzle (grids here are multiples of 8)
  const int nwg = gridDim.x * gridDim.y;
  const int orig = blockIdx.y * gridDim.x + blockIdx.x;
  const int q = nwg >> 3, r = nwg & 7;
  const int xcd = orig & 7, lid = orig >> 3;
  const int swz = (xcd < r ? xcd * (q + 1) : r * (q + 1) + (xcd - r) * q) + lid;
  const int bm = (swz / gridDim.x) * 128;
  const int bn = (swz % gridDim.x) * 128;

  const int wr = (wid >> 1) * 64;
  const int wc = (wid & 1) * 64;
  const int row16 = lane & 15;
  const int kgrp = lane >> 4;

  // staging: wave w, instr j in {0,1} covers rows j*64 + w*16 .. +15
  const int srow = wid * 16 + (lane >> 2);  // 0..63
  const int scol = (lane & 3) * 8;          // elements
  const unsigned short* gA = A + (size_t)(bm + srow) * K + scol;
  const unsigned short* gB = B + (size_t)(bn + srow) * K + scol;
  unsigned short* lA0 = &As[wid * 16][0];
  unsigned short* lA1 = &As[64 + wid * 16][0];
  unsigned short* lB0 = &Bs[wid * 16][0];
  unsigned short* lB1 = &Bs[64 + wid * 16][0];
  const size_t K64 = (size_t)64 * K;

  f32x4 acc[4][4] = {};

  for (int k0 = 0; k0 < K; k0 += 32) {
    gl_lds16(gA + k0, lA0);
    gl_lds16(gA + K64 + k0, lA1);
    gl_lds16(gB + k0, lB0);
    gl_lds16(gB + K64 + k0, lB1);
    __syncthreads();  // compiler drains vmcnt(0) before s_barrier
    bf16x8 af[4], bfr[4];
#pragma unroll
    for (int mi = 0; mi < 4; ++mi)
      af[mi] = *reinterpret_cast<const bf16x8*>(&As[wr + mi * 16 + row16][kgrp * 8]);
#pragma unroll
    for (int ni = 0; ni < 4; ++ni)
      bfr[ni] = *reinterpret_cast<const bf16x8*>(&Bs[wc + ni * 16 + row16][kgrp * 8]);
#pragma unroll
    for (int mi = 0; mi < 4; ++mi)
#pragma unroll
      for (int ni = 0; ni < 4; ++ni)
        acc[mi][ni] = __builtin_amdgcn_mfma_f32_16x16x32_bf16(af[mi], bfr[ni],
                                                              acc[mi][ni], 0, 0, 0);
    __syncthreads();
  }

#pragma unroll
  for (int ni = 0; ni < 4; ++ni) {
    const int gcol = bn + wc + ni * 16 + row16;
    const float bv = bias[gcol];
#pragma unroll
    for (int mi = 0; mi < 4; ++mi) {
#pragma unroll
      for (int r2 = 0; r2 < 4; ++r2) {
        const int grow = bm + wr + mi * 16 + kgrp * 4 + r2;
        const float val = acc[mi][ni][r2] + bv;
        if (OUT_BF16)
          reinterpret_cast<unsigned short*>(Cv)[(size_t)grow * N + gcol] = f2bf(val);
        else
          reinterpret_cast<float*>(Cv)[(size_t)grow * N + gcol] = val;
      }
    }
  }
}

// ---------------- local (banded) attention, v3 ----------------
__global__ __launch_bounds__(256) void attn_local(
    const unsigned short* __restrict__ qkv, unsigned short* __restrict__ ctx,
    int S) {
  __shared__ unsigned Vt[64][76];            // 19456 B; stride 304B (16B-aligned)
  __shared__ unsigned short Ps[4][16][104];  // 13312 B

  const int tid = threadIdx.x;
  const int lane = tid & 63;
  const int wid = tid >> 6;
  const int q0 = blockIdx.x * 64;
  const int b = blockIdx.y >> 3;
  const int h = blockIdx.y & 7;
  const int row16 = lane & 15;
  const int kgrp = lane >> 4;
  const size_t bS = (size_t)b * S;

  // ---- stage V transposed (packed key pairs) ----
  {
    const int k2 = tid >> 2;
    const int dq = (tid & 3) * 16;
    const int ra = iclamp(q0 - 32 + 2 * k2, 0, S - 1);
    const int rb = iclamp(q0 - 32 + 2 * k2 + 1, 0, S - 1);
    const unsigned short* pa = qkv + (bS + ra) * 1536 + 1024 + h * 64 + dq;
    const unsigned short* pb = qkv + (bS + rb) * 1536 + 1024 + h * 64 + dq;
    ushort8 a0 = reinterpret_cast<const ushort8*>(pa)[0];
    ushort8 a1 = reinterpret_cast<const ushort8*>(pa)[1];
    ushort8 b0 = reinterpret_cast<const ushort8*>(pb)[0];
    ushort8 b1 = reinterpret_cast<const ushort8*>(pb)[1];
#pragma unroll
    for (int d = 0; d < 8; ++d) {
      Vt[dq + d][k2] = (unsigned)a0[d] | ((unsigned)b0[d] << 16);
      Vt[dq + 8 + d][k2] = (unsigned)a1[d] | ((unsigned)b1[d] << 16);
    }
    // zero tail dwords 64..71 (keys 128..143: P=0 there, V must be finite)
    const int zr = tid >> 2;
    const int zc = 64 + (tid & 3) * 2;
    Vt[zr][zc] = 0u;
    Vt[zr][zc + 1] = 0u;
  }

  // ---- Q fragments (direct from global) ----
  bf16x8 qf0, qf1;
  {
    const unsigned short* qp =
        qkv + (bS + q0 + wid * 16 + row16) * 1536 + h * 64;
    qf0 = *reinterpret_cast<const bf16x8*>(qp + kgrp * 8);
    qf1 = *reinterpret_cast<const bf16x8*>(qp + 32 + kgrp * 8);
  }

  // ---- QK^T: 5 key tiles, K direct from global (clamped rows) ----
  f32x4 sc[5];
#pragma unroll
  for (int t = 0; t < 5; ++t) {
    const int key = iclamp(q0 - 32 + (wid + t) * 16 + row16, 0, S - 1);
    const unsigned short* kp = qkv + (bS + key) * 1536 + 512 + h * 64;
    bf16x8 kf0 = *reinterpret_cast<const bf16x8*>(kp + kgrp * 8);
    bf16x8 kf1 = *reinterpret_cast<const bf16x8*>(kp + 32 + kgrp * 8);
    f32x4 s = {0.f, 0.f, 0.f, 0.f};
    s = __builtin_amdgcn_mfma_f32_16x16x32_bf16(qf0, kf0, s, 0, 0, 0);
    s = __builtin_amdgcn_mfma_f32_16x16x32_bf16(qf1, kf1, s, 0, 0, 0);
    sc[t] = s;
  }

  // ---- mask + softmax ----
  const int ccol = row16;
  const int crow4 = kgrp * 4;
  float rm[4] = {-INFINITY, -INFINITY, -INFINITY, -INFINITY};
#pragma unroll
  for (int t = 0; t < 5; ++t)
#pragma unroll
    for (int r = 0; r < 4; ++r) {
      const int key_abs = q0 - 32 + (wid + t) * 16 + ccol;
      const int diff = -32 + t * 16 + ccol - crow4 - r;
      float s = sc[t][r] * 0.125f;
      const bool valid =
          (diff >= -32) && (diff <= 32) && (key_abs >= 0) && (key_abs < S);
      s = valid ? s : -INFINITY;
      sc[t][r] = s;
      rm[r] = fmaxf(rm[r], s);
    }
#pragma unroll
  for (int off = 1; off < 16; off <<= 1)
#pragma unroll
    for (int r = 0; r < 4; ++r) rm[r] = fmaxf(rm[r], __shfl_xor(rm[r], off, 64));
  float rs[4] = {0.f, 0.f, 0.f, 0.f};
#pragma unroll
  for (int t = 0; t < 5; ++t)
#pragma unroll
    for (int r = 0; r < 4; ++r) {
      const float p = __expf(sc[t][r] - rm[r]);
      sc[t][r] = p;
      rs[r] += p;
    }
#pragma unroll
  for (int off = 1; off < 16; off <<= 1)
#pragma unroll
    for (int r = 0; r < 4; ++r) rs[r] += __shfl_xor(rs[r], off, 64);

  // ---- P -> LDS (bf16), zero-pad keys 80..95 ----
#pragma unroll
  for (int t = 0; t < 5; ++t)
#pragma unroll
    for (int r = 0; r < 4; ++r)
      Ps[wid][crow4 + r][t * 16 + ccol] = f2bf(sc[t][r]);
#pragma unroll
  for (int j = 0; j < 4; ++j) Ps[wid][row16][80 + kgrp * 4 + j] = 0;

  __syncthreads();

  // ---- PV: ctx[16x64] = P[16x96] * V[96x64] ----
  f32x4 cacc[4] = {};
#pragma unroll
  for (int kc = 0; kc < 3; ++kc) {
    bf16x8 pf = *reinterpret_cast<const bf16x8*>(&Ps[wid][row16][kc * 32 + kgrp * 8]);
#pragma unroll
    for (int ni = 0; ni < 4; ++ni) {
      bf16x8 vf = *reinterpret_cast<const bf16x8*>(
          &Vt[ni * 16 + row16][wid * 8 + kc * 16 + kgrp * 4]);
      cacc[ni] = __builtin_amdgcn_mfma_f32_16x16x32_bf16(pf, vf, cacc[ni], 0, 0, 0);
    }
  }

  // ---- normalize + store ----
  float inv[4];
#pragma unroll
  for (int r = 0; r < 4; ++r) inv[r] = 1.0f / rs[r];
#pragma unroll
  for (int ni = 0; ni < 4; ++ni)
#pragma unroll
    for (int r = 0; r < 4; ++r) {
      const size_t off =
          (bS + q0 + wid * 16 + crow4 + r) * 512 + h * 64 + ni * 16 + ccol;
      ctx[off] = f2bf(cacc[ni][r] * inv[r]);
    }
}

extern "C" void kernel_launch(void* const* d_in, const int* in_sizes, int n_in,
                              void* d_out, int out_size, void* d_ws, size_t ws_size,
                              hipStream_t stream) {
  const float* x = (const float*)d_in[0];
  const float* w_in = (const float*)d_in[1];
  const float* b_in = (const float*)d_in[2];
  const float* w_out = (const float*)d_in[3];
  const float* b_out = (const float*)d_in[4];
  float* out = (float*)d_out;

  const int B = 2, S = 4096, D = 512;
  const int BS = B * S;  // 8192

  char* ws = (char*)d_ws;
  unsigned short* xb = (unsigned short*)(ws + 0);          //  8,388,608
  unsigned short* wbin = (unsigned short*)(ws + 8388608);  //  1,572,864
  unsigned short* wbo = (unsigned short*)(ws + 9961472);   //    524,288
  unsigned short* qkvb = (unsigned short*)(ws + 10485760); // 25,165,824
  unsigned short* ctxb = (unsigned short*)(ws + 35651584); //  8,388,608

  cvt_kernel<<<1024, 256, 0, stream>>>(x, xb, BS * D);
  cvt_kernel<<<512, 256, 0, stream>>>(w_in, wbin, 3 * D * D);
  cvt_kernel<<<256, 256, 0, stream>>>(w_out, wbo, D * D);

  // QKV projection: [8192,512] x [1536,512]^T -> bf16 [8192,1536]
  gemm_bt<1><<<dim3(12, 64), 256, 0, stream>>>(xb, wbin, b_in, qkvb, BS, 3 * D, D);

  // local attention -> ctx bf16 [8192,512]
  attn_local<<<dim3(S / 64, 16), 256, 0, stream>>>(qkvb, ctxb, S);

  // out projection: [8192,512] x [512,512]^T -> fp32 d_out
  gemm_bt<0><<<dim3(4, 64), 256, 0, stream>>>(ctxb, wbo, b_out, out, BS, D, D);
}

// Round 5
// 60.575 us; speedup vs baseline: 2.0659x; 1.0992x over previous
//
#include <hip/hip_runtime.h>

typedef __attribute__((ext_vector_type(8))) short bf16x8;
typedef __attribute__((ext_vector_type(8))) unsigned short ushort8;
typedef __attribute__((ext_vector_type(4))) float f32x4;

static __device__ __forceinline__ unsigned short f2bf(float f) {
  union { float f; unsigned u; } v; v.f = f;
  unsigned r = v.u + 0x7FFFu + ((v.u >> 16) & 1u);
  return (unsigned short)(r >> 16);
}
static __device__ __forceinline__ int iclamp(int x, int lo, int hi) {
  return x < lo ? lo : (x > hi ? hi : x);
}
// async global->LDS, 16B per lane; LDS dest = wave-uniform base + lane*16
static __device__ __forceinline__ void gl_lds16(const unsigned short* g,
                                                unsigned short* l) {
  __builtin_amdgcn_global_load_lds(
      (const __attribute__((address_space(1))) void*)g,
      (__attribute__((address_space(3))) void*)l, 16, 0, 0);
}

// ---------------- fused fp32 -> bf16 converts (one launch) ----------------
__global__ void cvt_all(const float* __restrict__ x,
                        const float* __restrict__ w_in,
                        const float* __restrict__ w_out,
                        unsigned short* __restrict__ xb,
                        unsigned short* __restrict__ wbin,
                        unsigned short* __restrict__ wbo) {
  const int NX4 = 1048576, NWI4 = 196608, NWO4 = 65536;  // float4 counts
  const int total = NX4 + NWI4 + NWO4;
  for (int i = blockIdx.x * blockDim.x + threadIdx.x; i < total;
       i += gridDim.x * blockDim.x) {
    const float* src;
    unsigned short* dst;
    int o;
    if (i < NX4) {
      src = x; dst = xb; o = i;
    } else if (i < NX4 + NWI4) {
      src = w_in; dst = wbin; o = i - NX4;
    } else {
      src = w_out; dst = wbo; o = i - NX4 - NWI4;
    }
    float4 v = reinterpret_cast<const float4*>(src)[o];
    ushort4 u;
    u.x = f2bf(v.x); u.y = f2bf(v.y); u.z = f2bf(v.z); u.w = f2bf(v.w);
    reinterpret_cast<ushort4*>(dst)[o] = u;
  }
}

// ---------------- GEMM: C[M][N] = A[M][K](bf16) * B[N][K](bf16)^T + bias ----------
// 128x128 tile, BK=64, linear LDS + global_load_lds w16 with pre-swizzled source.
// Swizzle (T2/T21): LDS[row][chunk] holds global[row][chunk ^ (row&7)], chunk=16B.
// Stage instrs use 8-aligned row bases, so row&7 == lane>>3 and the per-lane
// source chunk is (lane&7) ^ (lane>>3). Reads XOR the same involution.
template <int OUT_BF16>
__global__ __launch_bounds__(256) void gemm_bt(
    const unsigned short* __restrict__ A, const unsigned short* __restrict__ B,
    const float* __restrict__ bias, void* __restrict__ Cv,
    int M, int N, int K) {
  __shared__ unsigned short As[128][64];  // 16 KB, linear (no pad)
  __shared__ unsigned short Bs[128][64];
  const int tid = threadIdx.x;
  const int lane = tid & 63;
  const int wid = tid >> 6;

  // XCD-aware bijective swizzle (grids here are multiples of 8)
  const int nwg = gridDim.x * gridDim.y;
  const int orig = blockIdx.y * gridDim.x + blockIdx.x;
  const int q = nwg >> 3, r = nwg & 7;
  const int xcd = orig & 7, lid = orig >> 3;
  const int swz = (xcd < r ? xcd * (q + 1) : r * (q + 1) + (xcd - r) * q) + lid;
  const int bm = (swz / gridDim.x) * 128;
  const int bn = (swz % gridDim.x) * 128;

  const int wr = (wid >> 1) * 64;
  const int wc = (wid & 1) * 64;
  const int row16 = lane & 15;
  const int kgrp = lane >> 4;
  const int rsw = row16 & 7;  // read-side swizzle key

  // staging: wave covers rows wid*32 + j*8 .. +7 per instr j in 0..3
  const int srow = wid * 32 + (lane >> 3);               // + j*8
  const int schunk = ((lane & 7) ^ (lane >> 3)) * 8;     // swizzled source col
  const unsigned short* gA = A + (size_t)(bm + srow) * K + schunk;
  const unsigned short* gB = B + (size_t)(bn + srow) * K + schunk;
  const size_t K8 = (size_t)8 * K;

  f32x4 acc[4][4] = {};

  for (int k0 = 0; k0 < K; k0 += 64) {
#pragma unroll
    for (int j = 0; j < 4; ++j)
      gl_lds16(gA + j * K8 + k0, &As[wid * 32 + j * 8][0]);
#pragma unroll
    for (int j = 0; j < 4; ++j)
      gl_lds16(gB + j * K8 + k0, &Bs[wid * 32 + j * 8][0]);
    __syncthreads();  // drains vmcnt(0): LDS tiles complete
    bf16x8 af[4][2], bfr[4][2];
#pragma unroll
    for (int mi = 0; mi < 4; ++mi)
#pragma unroll
      for (int kh = 0; kh < 2; ++kh)
        af[mi][kh] = *reinterpret_cast<const bf16x8*>(
            &As[wr + mi * 16 + row16][((kh * 4 + kgrp) ^ rsw) * 8]);
#pragma unroll
    for (int ni = 0; ni < 4; ++ni)
#pragma unroll
      for (int kh = 0; kh < 2; ++kh)
        bfr[ni][kh] = *reinterpret_cast<const bf16x8*>(
            &Bs[wc + ni * 16 + row16][((kh * 4 + kgrp) ^ rsw) * 8]);
#pragma unroll
    for (int kh = 0; kh < 2; ++kh)
#pragma unroll
      for (int mi = 0; mi < 4; ++mi)
#pragma unroll
        for (int ni = 0; ni < 4; ++ni)
          acc[mi][ni] = __builtin_amdgcn_mfma_f32_16x16x32_bf16(
              af[mi][kh], bfr[ni][kh], acc[mi][ni], 0, 0, 0);
    __syncthreads();
  }

#pragma unroll
  for (int ni = 0; ni < 4; ++ni) {
    const int gcol = bn + wc + ni * 16 + row16;
    const float bv = bias[gcol];
#pragma unroll
    for (int mi = 0; mi < 4; ++mi) {
#pragma unroll
      for (int r2 = 0; r2 < 4; ++r2) {
        const int grow = bm + wr + mi * 16 + kgrp * 4 + r2;
        const float val = acc[mi][ni][r2] + bv;
        if (OUT_BF16)
          reinterpret_cast<unsigned short*>(Cv)[(size_t)grow * N + gcol] = f2bf(val);
        else
          reinterpret_cast<float*>(Cv)[(size_t)grow * N + gcol] = val;
      }
    }
  }
}

// ---------------- local (banded) attention, v3 (unchanged) ----------------
__global__ __launch_bounds__(256) void attn_local(
    const unsigned short* __restrict__ qkv, unsigned short* __restrict__ ctx,
    int S) {
  __shared__ unsigned Vt[64][76];            // 19456 B
  __shared__ unsigned short Ps[4][16][104];  // 13312 B

  const int tid = threadIdx.x;
  const int lane = tid & 63;
  const int wid = tid >> 6;
  const int q0 = blockIdx.x * 64;
  const int b = blockIdx.y >> 3;
  const int h = blockIdx.y & 7;
  const int row16 = lane & 15;
  const int kgrp = lane >> 4;
  const size_t bS = (size_t)b * S;

  // ---- stage V transposed (packed key pairs) ----
  {
    const int k2 = tid >> 2;
    const int dq = (tid & 3) * 16;
    const int ra = iclamp(q0 - 32 + 2 * k2, 0, S - 1);
    const int rb = iclamp(q0 - 32 + 2 * k2 + 1, 0, S - 1);
    const unsigned short* pa = qkv + (bS + ra) * 1536 + 1024 + h * 64 + dq;
    const unsigned short* pb = qkv + (bS + rb) * 1536 + 1024 + h * 64 + dq;
    ushort8 a0 = reinterpret_cast<const ushort8*>(pa)[0];
    ushort8 a1 = reinterpret_cast<const ushort8*>(pa)[1];
    ushort8 b0 = reinterpret_cast<const ushort8*>(pb)[0];
    ushort8 b1 = reinterpret_cast<const ushort8*>(pb)[1];
#pragma unroll
    for (int d = 0; d < 8; ++d) {
      Vt[dq + d][k2] = (unsigned)a0[d] | ((unsigned)b0[d] << 16);
      Vt[dq + 8 + d][k2] = (unsigned)a1[d] | ((unsigned)b1[d] << 16);
    }
    // zero tail dwords 64..71 (keys 128..143: P=0 there, V must be finite)
    const int zr = tid >> 2;
    const int zc = 64 + (tid & 3) * 2;
    Vt[zr][zc] = 0u;
    Vt[zr][zc + 1] = 0u;
  }

  // ---- Q fragments (direct from global) ----
  bf16x8 qf0, qf1;
  {
    const unsigned short* qp =
        qkv + (bS + q0 + wid * 16 + row16) * 1536 + h * 64;
    qf0 = *reinterpret_cast<const bf16x8*>(qp + kgrp * 8);
    qf1 = *reinterpret_cast<const bf16x8*>(qp + 32 + kgrp * 8);
  }

  // ---- QK^T: 5 key tiles, K direct from global (clamped rows) ----
  f32x4 sc[5];
#pragma unroll
  for (int t = 0; t < 5; ++t) {
    const int key = iclamp(q0 - 32 + (wid + t) * 16 + row16, 0, S - 1);
    const unsigned short* kp = qkv + (bS + key) * 1536 + 512 + h * 64;
    bf16x8 kf0 = *reinterpret_cast<const bf16x8*>(kp + kgrp * 8);
    bf16x8 kf1 = *reinterpret_cast<const bf16x8*>(kp + 32 + kgrp * 8);
    f32x4 s = {0.f, 0.f, 0.f, 0.f};
    s = __builtin_amdgcn_mfma_f32_16x16x32_bf16(qf0, kf0, s, 0, 0, 0);
    s = __builtin_amdgcn_mfma_f32_16x16x32_bf16(qf1, kf1, s, 0, 0, 0);
    sc[t] = s;
  }

  // ---- mask + softmax ----
  const int ccol = row16;
  const int crow4 = kgrp * 4;
  float rm[4] = {-INFINITY, -INFINITY, -INFINITY, -INFINITY};
#pragma unroll
  for (int t = 0; t < 5; ++t)
#pragma unroll
    for (int r = 0; r < 4; ++r) {
      const int key_abs = q0 - 32 + (wid + t) * 16 + ccol;
      const int diff = -32 + t * 16 + ccol - crow4 - r;
      float s = sc[t][r] * 0.125f;
      const bool valid =
          (diff >= -32) && (diff <= 32) && (key_abs >= 0) && (key_abs < S);
      s = valid ? s : -INFINITY;
      sc[t][r] = s;
      rm[r] = fmaxf(rm[r], s);
    }
#pragma unroll
  for (int off = 1; off < 16; off <<= 1)
#pragma unroll
    for (int r = 0; r < 4; ++r) rm[r] = fmaxf(rm[r], __shfl_xor(rm[r], off, 64));
  float rs[4] = {0.f, 0.f, 0.f, 0.f};
#pragma unroll
  for (int t = 0; t < 5; ++t)
#pragma unroll
    for (int r = 0; r < 4; ++r) {
      const float p = __expf(sc[t][r] - rm[r]);
      sc[t][r] = p;
      rs[r] += p;
    }
#pragma unroll
  for (int off = 1; off < 16; off <<= 1)
#pragma unroll
    for (int r = 0; r < 4; ++r) rs[r] += __shfl_xor(rs[r], off, 64);

  // ---- P -> LDS (bf16), zero-pad keys 80..95 ----
#pragma unroll
  for (int t = 0; t < 5; ++t)
#pragma unroll
    for (int r = 0; r < 4; ++r)
      Ps[wid][crow4 + r][t * 16 + ccol] = f2bf(sc[t][r]);
#pragma unroll
  for (int j = 0; j < 4; ++j) Ps[wid][row16][80 + kgrp * 4 + j] = 0;

  __syncthreads();

  // ---- PV: ctx[16x64] = P[16x96] * V[96x64] ----
  f32x4 cacc[4] = {};
#pragma unroll
  for (int kc = 0; kc < 3; ++kc) {
    bf16x8 pf = *reinterpret_cast<const bf16x8*>(&Ps[wid][row16][kc * 32 + kgrp * 8]);
#pragma unroll
    for (int ni = 0; ni < 4; ++ni) {
      bf16x8 vf = *reinterpret_cast<const bf16x8*>(
          &Vt[ni * 16 + row16][wid * 8 + kc * 16 + kgrp * 4]);
      cacc[ni] = __builtin_amdgcn_mfma_f32_16x16x32_bf16(pf, vf, cacc[ni], 0, 0, 0);
    }
  }

  // ---- normalize + store ----
  float inv[4];
#pragma unroll
  for (int r = 0; r < 4; ++r) inv[r] = 1.0f / rs[r];
#pragma unroll
  for (int ni = 0; ni < 4; ++ni)
#pragma unroll
    for (int r = 0; r < 4; ++r) {
      const size_t off =
          (bS + q0 + wid * 16 + crow4 + r) * 512 + h * 64 + ni * 16 + ccol;
      ctx[off] = f2bf(cacc[ni][r] * inv[r]);
    }
}

extern "C" void kernel_launch(void* const* d_in, const int* in_sizes, int n_in,
                              void* d_out, int out_size, void* d_ws, size_t ws_size,
                              hipStream_t stream) {
  const float* x = (const float*)d_in[0];
  const float* w_in = (const float*)d_in[1];
  const float* b_in = (const float*)d_in[2];
  const float* w_out = (const float*)d_in[3];
  const float* b_out = (const float*)d_in[4];
  float* out = (float*)d_out;

  const int B = 2, S = 4096, D = 512;
  const int BS = B * S;  // 8192

  char* ws = (char*)d_ws;
  unsigned short* xb = (unsigned short*)(ws + 0);          //  8,388,608
  unsigned short* wbin = (unsigned short*)(ws + 8388608);  //  1,572,864
  unsigned short* wbo = (unsigned short*)(ws + 9961472);   //    524,288
  unsigned short* qkvb = (unsigned short*)(ws + 10485760); // 25,165,824
  unsigned short* ctxb = (unsigned short*)(ws + 35651584); //  8,388,608

  // all fp32->bf16 converts in one launch
  cvt_all<<<2048, 256, 0, stream>>>(x, w_in, w_out, xb, wbin, wbo);

  // QKV projection: [8192,512] x [1536,512]^T -> bf16 [8192,1536]
  gemm_bt<1><<<dim3(12, 64), 256, 0, stream>>>(xb, wbin, b_in, qkvb, BS, 3 * D, D);

  // local attention -> ctx bf16 [8192,512]
  attn_local<<<dim3(S / 64, 16), 256, 0, stream>>>(qkvb, ctxb, S);

  // out projection: [8192,512] x [512,512]^T -> fp32 d_out
  gemm_bt<0><<<dim3(4, 64), 256, 0, stream>>>(ctxb, wbo, b_out, out, BS, D, D);
}

// Round 6
// 56.927 us; speedup vs baseline: 2.1983x; 1.0641x over previous
//
#include <hip/hip_runtime.h>

typedef __attribute__((ext_vector_type(8))) short bf16x8;
typedef __attribute__((ext_vector_type(8))) unsigned short ushort8;
typedef __attribute__((ext_vector_type(4))) float f32x4;

static __device__ __forceinline__ unsigned short f2bf(float f) {
  union { float f; unsigned u; } v; v.f = f;
  unsigned r = v.u + 0x7FFFu + ((v.u >> 16) & 1u);
  return (unsigned short)(r >> 16);
}
static __device__ __forceinline__ int iclamp(int x, int lo, int hi) {
  return x < lo ? lo : (x > hi ? hi : x);
}
// async global->LDS, 16B per lane; LDS dest = wave-uniform base + lane*16
static __device__ __forceinline__ void gl_lds16(const unsigned short* g,
                                                unsigned short* l) {
  __builtin_amdgcn_global_load_lds(
      (const __attribute__((address_space(1))) void*)g,
      (__attribute__((address_space(3))) void*)l, 16, 0, 0);
}

// ---------------- fused fp32 -> bf16 converts (one launch) ----------------
__global__ void cvt_all(const float* __restrict__ x,
                        const float* __restrict__ w_in,
                        const float* __restrict__ w_out,
                        unsigned short* __restrict__ xb,
                        unsigned short* __restrict__ wbin,
                        unsigned short* __restrict__ wbo) {
  const int NX4 = 1048576, NWI4 = 196608, NWO4 = 65536;  // float4 counts
  const int total = NX4 + NWI4 + NWO4;
  for (int i = blockIdx.x * blockDim.x + threadIdx.x; i < total;
       i += gridDim.x * blockDim.x) {
    const float* src;
    unsigned short* dst;
    int o;
    if (i < NX4) {
      src = x; dst = xb; o = i;
    } else if (i < NX4 + NWI4) {
      src = w_in; dst = wbin; o = i - NX4;
    } else {
      src = w_out; dst = wbo; o = i - NX4 - NWI4;
    }
    float4 v = reinterpret_cast<const float4*>(src)[o];
    ushort4 u;
    u.x = f2bf(v.x); u.y = f2bf(v.y); u.z = f2bf(v.z); u.w = f2bf(v.w);
    reinterpret_cast<ushort4*>(dst)[o] = u;
  }
}

// ------- GEMM: C[M][N] = A[M][K](bf16) * B[N][K](bf16)^T + bias -------
// BMxBN tile, BK=64, double-buffered linear LDS staged by global_load_lds w16
// with pre-swizzled source (T21 both-sides XOR involution, chunk ^= row&7).
// 2-phase pipeline: STAGE(next) issued BEFORE compute(cur); drain with raw
// "s_waitcnt vmcnt(0)" + s_barrier AFTER the MFMAs (latency hidden under MFMA).
// One barrier per K-step. 4 waves, each computes WMxWN.
template <int BM, int BN, int WM, int WN, int OUT_BF16>
__global__ __launch_bounds__(256) void gemm_bt(
    const unsigned short* __restrict__ A, const unsigned short* __restrict__ B,
    const float* __restrict__ bias, void* __restrict__ Cv,
    int M, int N, int K) {
  __shared__ unsigned short As[2][BM][64];
  __shared__ unsigned short Bs[2][BN][64];
  const int tid = threadIdx.x;
  const int lane = tid & 63;
  const int wid = tid >> 6;

  // XCD-aware bijective swizzle (grids here are multiples of 8)
  const int nwg = gridDim.x * gridDim.y;
  const int orig = blockIdx.y * gridDim.x + blockIdx.x;
  const int q = nwg >> 3, r = nwg & 7;
  const int xcd = orig & 7, lid = orig >> 3;
  const int swz = (xcd < r ? xcd * (q + 1) : r * (q + 1) + (xcd - r) * q) + lid;
  const int bm = (swz / gridDim.x) * BM;
  const int bn = (swz % gridDim.x) * BN;

  const int NWC = BN / WN;  // waves along N
  const int wr = (wid / NWC) * WM;
  const int wc = (wid % NWC) * WN;
  const int row16 = lane & 15;
  const int kgrp = lane >> 4;
  const int rsw = row16 & 7;  // read-side swizzle key

  // staging: one gl_lds16 instr = 64 lanes x 16B = 8 rows of 64 elems
  const int srA = wid * (BM / 4) + (lane >> 3);
  const int srB = wid * (BN / 4) + (lane >> 3);
  const int schunk = ((lane & 7) ^ (lane >> 3)) * 8;  // swizzled source col
  const unsigned short* gA = A + (size_t)(bm + srA) * K + schunk;
  const unsigned short* gB = B + (size_t)(bn + srB) * K + schunk;
  const size_t K8 = (size_t)8 * K;

#define STAGE(buf, k0)                                                   \
  {                                                                      \
    _Pragma("unroll") for (int j = 0; j < BM / 32; ++j)                  \
        gl_lds16(gA + j * K8 + (k0), &As[buf][wid * (BM / 4) + j * 8][0]); \
    _Pragma("unroll") for (int j = 0; j < BN / 32; ++j)                  \
        gl_lds16(gB + j * K8 + (k0), &Bs[buf][wid * (BN / 4) + j * 8][0]); \
  }

  f32x4 acc[WM / 16][WN / 16] = {};

  STAGE(0, 0);
  asm volatile("s_waitcnt vmcnt(0)" ::: "memory");
  __builtin_amdgcn_s_barrier();

  const int NT = K >> 6;  // K/64
  for (int t = 0; t < NT; ++t) {
    const int cur = t & 1;
    if (t + 1 < NT) STAGE(cur ^ 1, (t + 1) * 64);
    bf16x8 af[WM / 16][2], bfr[WN / 16][2];
#pragma unroll
    for (int mi = 0; mi < WM / 16; ++mi)
#pragma unroll
      for (int kh = 0; kh < 2; ++kh)
        af[mi][kh] = *reinterpret_cast<const bf16x8*>(
            &As[cur][wr + mi * 16 + row16][((kh * 4 + kgrp) ^ rsw) * 8]);
#pragma unroll
    for (int ni = 0; ni < WN / 16; ++ni)
#pragma unroll
      for (int kh = 0; kh < 2; ++kh)
        bfr[ni][kh] = *reinterpret_cast<const bf16x8*>(
            &Bs[cur][wc + ni * 16 + row16][((kh * 4 + kgrp) ^ rsw) * 8]);
#pragma unroll
    for (int kh = 0; kh < 2; ++kh)
#pragma unroll
      for (int mi = 0; mi < WM / 16; ++mi)
#pragma unroll
        for (int ni = 0; ni < WN / 16; ++ni)
          acc[mi][ni] = __builtin_amdgcn_mfma_f32_16x16x32_bf16(
              af[mi][kh], bfr[ni][kh], acc[mi][ni], 0, 0, 0);
    // drain next-tile loads AFTER compute (latency covered), then barrier
    asm volatile("s_waitcnt vmcnt(0)" ::: "memory");
    __builtin_amdgcn_s_barrier();
  }
#undef STAGE

#pragma unroll
  for (int ni = 0; ni < WN / 16; ++ni) {
    const int gcol = bn + wc + ni * 16 + row16;
    const float bv = bias[gcol];
#pragma unroll
    for (int mi = 0; mi < WM / 16; ++mi) {
#pragma unroll
      for (int r2 = 0; r2 < 4; ++r2) {
        const int grow = bm + wr + mi * 16 + kgrp * 4 + r2;
        const float val = acc[mi][ni][r2] + bv;
        if (OUT_BF16)
          reinterpret_cast<unsigned short*>(Cv)[(size_t)grow * N + gcol] = f2bf(val);
        else
          reinterpret_cast<float*>(Cv)[(size_t)grow * N + gcol] = val;
      }
    }
  }
}

// ---------------- local (banded) attention, v3 (unchanged) ----------------
__global__ __launch_bounds__(256) void attn_local(
    const unsigned short* __restrict__ qkv, unsigned short* __restrict__ ctx,
    int S) {
  __shared__ unsigned Vt[64][76];            // 19456 B
  __shared__ unsigned short Ps[4][16][104];  // 13312 B

  const int tid = threadIdx.x;
  const int lane = tid & 63;
  const int wid = tid >> 6;
  const int q0 = blockIdx.x * 64;
  const int b = blockIdx.y >> 3;
  const int h = blockIdx.y & 7;
  const int row16 = lane & 15;
  const int kgrp = lane >> 4;
  const size_t bS = (size_t)b * S;

  // ---- stage V transposed (packed key pairs) ----
  {
    const int k2 = tid >> 2;
    const int dq = (tid & 3) * 16;
    const int ra = iclamp(q0 - 32 + 2 * k2, 0, S - 1);
    const int rb = iclamp(q0 - 32 + 2 * k2 + 1, 0, S - 1);
    const unsigned short* pa = qkv + (bS + ra) * 1536 + 1024 + h * 64 + dq;
    const unsigned short* pb = qkv + (bS + rb) * 1536 + 1024 + h * 64 + dq;
    ushort8 a0 = reinterpret_cast<const ushort8*>(pa)[0];
    ushort8 a1 = reinterpret_cast<const ushort8*>(pa)[1];
    ushort8 b0 = reinterpret_cast<const ushort8*>(pb)[0];
    ushort8 b1 = reinterpret_cast<const ushort8*>(pb)[1];
#pragma unroll
    for (int d = 0; d < 8; ++d) {
      Vt[dq + d][k2] = (unsigned)a0[d] | ((unsigned)b0[d] << 16);
      Vt[dq + 8 + d][k2] = (unsigned)a1[d] | ((unsigned)b1[d] << 16);
    }
    // zero tail dwords 64..71 (keys 128..143: P=0 there, V must be finite)
    const int zr = tid >> 2;
    const int zc = 64 + (tid & 3) * 2;
    Vt[zr][zc] = 0u;
    Vt[zr][zc + 1] = 0u;
  }

  // ---- Q fragments (direct from global) ----
  bf16x8 qf0, qf1;
  {
    const unsigned short* qp =
        qkv + (bS + q0 + wid * 16 + row16) * 1536 + h * 64;
    qf0 = *reinterpret_cast<const bf16x8*>(qp + kgrp * 8);
    qf1 = *reinterpret_cast<const bf16x8*>(qp + 32 + kgrp * 8);
  }

  // ---- QK^T: 5 key tiles, K direct from global (clamped rows) ----
  f32x4 sc[5];
#pragma unroll
  for (int t = 0; t < 5; ++t) {
    const int key = iclamp(q0 - 32 + (wid + t) * 16 + row16, 0, S - 1);
    const unsigned short* kp = qkv + (bS + key) * 1536 + 512 + h * 64;
    bf16x8 kf0 = *reinterpret_cast<const bf16x8*>(kp + kgrp * 8);
    bf16x8 kf1 = *reinterpret_cast<const bf16x8*>(kp + 32 + kgrp * 8);
    f32x4 s = {0.f, 0.f, 0.f, 0.f};
    s = __builtin_amdgcn_mfma_f32_16x16x32_bf16(qf0, kf0, s, 0, 0, 0);
    s = __builtin_amdgcn_mfma_f32_16x16x32_bf16(qf1, kf1, s, 0, 0, 0);
    sc[t] = s;
  }

  // ---- mask + softmax ----
  const int ccol = row16;
  const int crow4 = kgrp * 4;
  float rm[4] = {-INFINITY, -INFINITY, -INFINITY, -INFINITY};
#pragma unroll
  for (int t = 0; t < 5; ++t)
#pragma unroll
    for (int r = 0; r < 4; ++r) {
      const int key_abs = q0 - 32 + (wid + t) * 16 + ccol;
      const int diff = -32 + t * 16 + ccol - crow4 - r;
      float s = sc[t][r] * 0.125f;
      const bool valid =
          (diff >= -32) && (diff <= 32) && (key_abs >= 0) && (key_abs < S);
      s = valid ? s : -INFINITY;
      sc[t][r] = s;
      rm[r] = fmaxf(rm[r], s);
    }
#pragma unroll
  for (int off = 1; off < 16; off <<= 1)
#pragma unroll
    for (int r = 0; r < 4; ++r) rm[r] = fmaxf(rm[r], __shfl_xor(rm[r], off, 64));
  float rs[4] = {0.f, 0.f, 0.f, 0.f};
#pragma unroll
  for (int t = 0; t < 5; ++t)
#pragma unroll
    for (int r = 0; r < 4; ++r) {
      const float p = __expf(sc[t][r] - rm[r]);
      sc[t][r] = p;
      rs[r] += p;
    }
#pragma unroll
  for (int off = 1; off < 16; off <<= 1)
#pragma unroll
    for (int r = 0; r < 4; ++r) rs[r] += __shfl_xor(rs[r], off, 64);

  // ---- P -> LDS (bf16), zero-pad keys 80..95 ----
#pragma unroll
  for (int t = 0; t < 5; ++t)
#pragma unroll
    for (int r = 0; r < 4; ++r)
      Ps[wid][crow4 + r][t * 16 + ccol] = f2bf(sc[t][r]);
#pragma unroll
  for (int j = 0; j < 4; ++j) Ps[wid][row16][80 + kgrp * 4 + j] = 0;

  __syncthreads();

  // ---- PV: ctx[16x64] = P[16x96] * V[96x64] ----
  f32x4 cacc[4] = {};
#pragma unroll
  for (int kc = 0; kc < 3; ++kc) {
    bf16x8 pf = *reinterpret_cast<const bf16x8*>(&Ps[wid][row16][kc * 32 + kgrp * 8]);
#pragma unroll
    for (int ni = 0; ni < 4; ++ni) {
      bf16x8 vf = *reinterpret_cast<const bf16x8*>(
          &Vt[ni * 16 + row16][wid * 8 + kc * 16 + kgrp * 4]);
      cacc[ni] = __builtin_amdgcn_mfma_f32_16x16x32_bf16(pf, vf, cacc[ni], 0, 0, 0);
    }
  }

  // ---- normalize + store ----
  float inv[4];
#pragma unroll
  for (int r = 0; r < 4; ++r) inv[r] = 1.0f / rs[r];
#pragma unroll
  for (int ni = 0; ni < 4; ++ni)
#pragma unroll
    for (int r = 0; r < 4; ++r) {
      const size_t off =
          (bS + q0 + wid * 16 + crow4 + r) * 512 + h * 64 + ni * 16 + ccol;
      ctx[off] = f2bf(cacc[ni][r] * inv[r]);
    }
}

extern "C" void kernel_launch(void* const* d_in, const int* in_sizes, int n_in,
                              void* d_out, int out_size, void* d_ws, size_t ws_size,
                              hipStream_t stream) {
  const float* x = (const float*)d_in[0];
  const float* w_in = (const float*)d_in[1];
  const float* b_in = (const float*)d_in[2];
  const float* w_out = (const float*)d_in[3];
  const float* b_out = (const float*)d_in[4];
  float* out = (float*)d_out;

  const int B = 2, S = 4096, D = 512;
  const int BS = B * S;  // 8192

  char* ws = (char*)d_ws;
  unsigned short* xb = (unsigned short*)(ws + 0);          //  8,388,608
  unsigned short* wbin = (unsigned short*)(ws + 8388608);  //  1,572,864
  unsigned short* wbo = (unsigned short*)(ws + 9961472);   //    524,288
  unsigned short* qkvb = (unsigned short*)(ws + 10485760); // 25,165,824
  unsigned short* ctxb = (unsigned short*)(ws + 35651584); //  8,388,608

  // all fp32->bf16 converts in one launch
  cvt_all<<<2048, 256, 0, stream>>>(x, w_in, w_out, xb, wbin, wbo);

  // QKV projection: [8192,512] x [1536,512]^T -> bf16 [8192,1536]
  gemm_bt<128, 128, 64, 64, 1>
      <<<dim3(12, 64), 256, 0, stream>>>(xb, wbin, b_in, qkvb, BS, 3 * D, D);

  // local attention -> ctx bf16 [8192,512]
  attn_local<<<dim3(S / 64, 16), 256, 0, stream>>>(qkvb, ctxb, S);

  // out projection: [8192,512] x [512,512]^T -> fp32 d_out; 64x128 tile ->
  // grid 4x128 = 512 blocks = 2/CU (128x128 gave exactly 1/CU: no overlap)
  gemm_bt<64, 128, 32, 64, 0>
      <<<dim3(4, 128), 256, 0, stream>>>(ctxb, wbo, b_out, out, BS, D, D);
}